// Round 4
// baseline (53.318 us; speedup 1.0000x reference)
//
#include <hip/hip_runtime.h>
#include <climits>

// Problem constants
#define VV 50257
#define DD 1024
#define BB 16
#define SS 2048
#define PP 10
#define AA 5
#define TT 64
#define LL (PP + SS + TT + AA)   // 2127
#define RPB 4                    // rows per block
#define NG  ((LL + RPB - 1) / RPB) // 532 row-groups

// Output element offsets (float32 elements, outputs concatenated flat in return order)
#define OFF_EMB ((size_t)0)
#define OFF_AM  ((size_t)BB * LL * DD)
#define OFF_TM  (OFF_AM + (size_t)BB * LL)
#define OFF_TI  (OFF_TM + (size_t)BB * LL)
#define OFF_S2  (OFF_TI + (size_t)BB * TT)
#define OFF_LAB (OFF_S2 + (size_t)BB)

typedef float f4 __attribute__((ext_vector_type(4)));

// Kernel 1: per-batch split computation ONLY (fast, 16 blocks)
__global__ void soft_emb_split(const int* __restrict__ attn_mask,   // (B,S)
                               int* __restrict__ ws_split)          // (B,)
{
    const int b = blockIdx.x;
    const int tid = threadIdx.x;
    __shared__ int red[256];

    const int* mrow = attn_mask + (size_t)b * SS;
    int fz = INT_MAX;
    for (int j = tid; j < SS; j += 256)
        if (mrow[j] == 0) fz = min(fz, j);
    red[tid] = fz;
    __syncthreads();
    for (int o = 128; o > 0; o >>= 1) {
        if (tid < o) red[tid] = min(red[tid], red[tid + o]);
        __syncthreads();
    }
    if (tid == 0) {
        const int first0 = red[0];
        ws_split[b] = (first0 == INT_MAX) ? 1 : (PP + first0 + 1);
    }
}

// Per-row source pointer (layout after both inserts at split s)
static __device__ __forceinline__ const float*
row_src(int j, int b, int s, int s2,
        const int* __restrict__ input_ids, const int* __restrict__ tgt_ids,
        const float* __restrict__ wte, const float* __restrict__ prep,
        const float* __restrict__ app)
{
    if (j < s) {
        return (j < PP) ? (prep + (size_t)j * DD)
                        : (wte + (size_t)input_ids[(size_t)b * SS + (j - PP)] * DD);
    } else if (j < s2) {
        return app + (size_t)(j - s) * DD;
    } else if (j < s2 + TT) {
        return wte + (size_t)tgt_ids[(size_t)b * TT + (j - s2)] * DD;
    } else {
        int k = j - AA - TT;
        return (k < PP) ? (prep + (size_t)k * DD)
                        : (wte + (size_t)input_ids[(size_t)b * SS + (k - PP)] * DD);
    }
}

// Kernel 2: grid (NG+1, BB).
//  blockIdx.x <  NG : copy RPB emb rows (4 independent float4 loads -> NT stores)
//  blockIdx.x == NG : all small outputs for batch b (overlaps with row copies)
__global__ void soft_emb_main(const int* __restrict__ input_ids,  // (B,S)
                              const int* __restrict__ attn_mask,  // (B,S)
                              const int* __restrict__ tgt_ids,    // (B,T)
                              const int* __restrict__ tgt_am,     // (B,T)
                              const float* __restrict__ wte,      // (V,D)
                              const float* __restrict__ prep,     // (P,D)
                              const float* __restrict__ app,      // (A,D)
                              const int* __restrict__ ws_split,   // (B,)
                              float* __restrict__ out)            // f32 flat
{
    const int g = blockIdx.x;
    const int b = blockIdx.y;
    const int tid = threadIdx.x;
    const int s = ws_split[b];
    const int s2 = s + AA;

    if (g < NG) {
        const int j0 = g * RPB;
        // 1) resolve all source pointers (independent index loads)
        const float* src[RPB];
        #pragma unroll
        for (int r = 0; r < RPB; ++r) {
            int j = j0 + r;
            src[r] = (j < LL) ? row_src(j, b, s, s2, input_ids, tgt_ids, wte, prep, app)
                              : nullptr;
        }
        // 2) issue all row loads (independent -> 4 in flight per lane)
        f4 v[RPB];
        #pragma unroll
        for (int r = 0; r < RPB; ++r)
            if (src[r]) v[r] = reinterpret_cast<const f4*>(src[r])[tid];
        // 3) NT stores
        #pragma unroll
        for (int r = 0; r < RPB; ++r) {
            int j = j0 + r;
            if (src[r]) {
                f4* dst = reinterpret_cast<f4*>(out + OFF_EMB + ((size_t)b * LL + j) * DD) + tid;
                __builtin_nontemporal_store(v[r], dst);
            }
        }
        return;
    }

    // ---- small outputs for batch b ----
    const int* mrow  = attn_mask + (size_t)b * SS;
    const int* trow  = tgt_ids   + (size_t)b * TT;
    const int* tmrow = tgt_am    + (size_t)b * TT;
    float* amo  = out + OFF_AM  + (size_t)b * LL;
    float* tmo  = out + OFF_TM  + (size_t)b * LL;
    float* labo = out + OFF_LAB + (size_t)b * LL;

    for (int i = tid; i < LL; i += 256) {
        // ---- am (after both inserts at split) ----
        float amv;
        if (i < s) {
            amv = (i < PP) ? 1.0f : (float)mrow[i - PP];
        } else if (i < s2) {
            amv = 1.0f;                              // appended ones
        } else if (i < s2 + TT) {
            amv = (float)tmrow[i - s2];              // target attention mask
        } else {
            int k = i - AA - TT;
            amv = (k < PP) ? 1.0f : (float)mrow[k - PP];
        }
        amo[i] = amv;

        // ---- target_mask, shifted right by 1 ----
        float tmv = 0.0f;
        if (i > 0) {
            int k = i - 1 - s2;
            if (k >= 0 && k < TT) tmv = (float)tmrow[k];
        }
        tmo[i] = tmv;

        // ---- labels, shifted left by 1 (last = -1) ----
        float lv = -1.0f;
        if (i < LL - 1) {
            int u = i + 1 - s2;
            if (u >= 0 && u < TT && tmrow[u] == 1) lv = (float)trow[u];
        }
        labo[i] = lv;
    }

    // ---- target_ids: input shifted left by 1, last = -1; and split2 ----
    if (tid < TT) {
        float tv = (tid == TT - 1) ? -1.0f : (float)trow[tid + 1];
        out[OFF_TI + (size_t)b * TT + tid] = tv;
    }
    if (tid == 0) out[OFF_S2 + b] = (float)s2;
}

extern "C" void kernel_launch(void* const* d_in, const int* in_sizes, int n_in,
                              void* d_out, int out_size, void* d_ws, size_t ws_size,
                              hipStream_t stream) {
    const int*   input_ids = (const int*)d_in[0];
    const int*   attn_mask = (const int*)d_in[1];
    const int*   tgt_ids   = (const int*)d_in[2];
    const int*   tgt_am    = (const int*)d_in[3];
    const float* wte       = (const float*)d_in[4];
    const float* prep      = (const float*)d_in[5];
    const float* app       = (const float*)d_in[6];
    float* out = (float*)d_out;
    int* ws = (int*)d_ws;

    soft_emb_split<<<BB, 256, 0, stream>>>(attn_mask, ws);
    soft_emb_main<<<dim3(NG + 1, BB), 256, 0, stream>>>(input_ids, attn_mask, tgt_ids, tgt_am,
                                                        wte, prep, app, ws, out);
}

// Round 5
// 49.596 us; speedup vs baseline: 1.0751x; 1.0751x over previous
//
#include <hip/hip_runtime.h>
#include <climits>

// Problem constants
#define VV 50257
#define DD 1024
#define BB 16
#define SS 2048
#define PP 10
#define AA 5
#define TT 64
#define LL (PP + SS + TT + AA)   // 2127
#define RPB 4                    // rows per block
#define NG  ((LL + RPB - 1) / RPB) // 532 row-groups

// Output element offsets (float32 elements, outputs concatenated flat in return order)
#define OFF_EMB ((size_t)0)
#define OFF_AM  ((size_t)BB * LL * DD)
#define OFF_TM  (OFF_AM + (size_t)BB * LL)
#define OFF_TI  (OFF_TM + (size_t)BB * LL)
#define OFF_S2  (OFF_TI + (size_t)BB * TT)
#define OFF_LAB (OFF_S2 + (size_t)BB)

typedef float f4 __attribute__((ext_vector_type(4)));
typedef int   i4 __attribute__((ext_vector_type(4)));

// Per-row source pointer (layout after both inserts at split s)
static __device__ __forceinline__ const float*
row_src(int j, int b, int s, int s2,
        const int* __restrict__ input_ids, const int* __restrict__ tgt_ids,
        const float* __restrict__ wte, const float* __restrict__ prep,
        const float* __restrict__ app)
{
    if (j < s) {
        return (j < PP) ? (prep + (size_t)j * DD)
                        : (wte + (size_t)input_ids[(size_t)b * SS + (j - PP)] * DD);
    } else if (j < s2) {
        return app + (size_t)(j - s) * DD;
    } else if (j < s2 + TT) {
        return wte + (size_t)tgt_ids[(size_t)b * TT + (j - s2)] * DD;
    } else {
        int k = j - AA - TT;
        return (k < PP) ? (prep + (size_t)k * DD)
                        : (wte + (size_t)input_ids[(size_t)b * SS + (k - PP)] * DD);
    }
}

// Single fused kernel: grid (NG+1, BB), 256 threads.
//  Every block first computes its batch's split s via coalesced scan + LDS min-reduce
//  (mask row is L2-resident after first touch).
//  blockIdx.x <  NG : copy RPB emb rows (independent float4 loads -> NT stores)
//  blockIdx.x == NG : all small outputs for batch b
__global__ void soft_emb_fused(const int* __restrict__ input_ids,  // (B,S)
                               const int* __restrict__ attn_mask,  // (B,S)
                               const int* __restrict__ tgt_ids,    // (B,T)
                               const int* __restrict__ tgt_am,     // (B,T)
                               const float* __restrict__ wte,      // (V,D)
                               const float* __restrict__ prep,     // (P,D)
                               const float* __restrict__ app,      // (A,D)
                               float* __restrict__ out)            // f32 flat
{
    const int g   = blockIdx.x;
    const int b   = blockIdx.y;
    const int tid = threadIdx.x;

    // ---- compute split s for batch b (256 threads x 8 ints = 2048 = SS) ----
    __shared__ int red[256];
    const int* mrow = attn_mask + (size_t)b * SS;
    {
        const i4* m4 = reinterpret_cast<const i4*>(mrow) + tid * 2;
        i4 a = m4[0];
        i4 c = m4[1];
        int base = tid * 8;
        int fz = INT_MAX;
        // first zero among my 8 (reverse order, min wins)
        if (c.w == 0) fz = base + 7;
        if (c.z == 0) fz = base + 6;
        if (c.y == 0) fz = base + 5;
        if (c.x == 0) fz = base + 4;
        if (a.w == 0) fz = base + 3;
        if (a.z == 0) fz = base + 2;
        if (a.y == 0) fz = base + 1;
        if (a.x == 0) fz = base + 0;
        red[tid] = fz;
    }
    __syncthreads();
    for (int o = 128; o > 0; o >>= 1) {
        if (tid < o) red[tid] = min(red[tid], red[tid + o]);
        __syncthreads();
    }
    const int first0 = red[0];
    const int s  = (first0 == INT_MAX) ? 1 : (PP + first0 + 1);
    const int s2 = s + AA;

    if (g < NG) {
        const int j0 = g * RPB;
        const float* src[RPB];
        #pragma unroll
        for (int r = 0; r < RPB; ++r) {
            int j = j0 + r;
            src[r] = (j < LL) ? row_src(j, b, s, s2, input_ids, tgt_ids, wte, prep, app)
                              : nullptr;
        }
        f4 v[RPB];
        #pragma unroll
        for (int r = 0; r < RPB; ++r)
            if (src[r]) v[r] = reinterpret_cast<const f4*>(src[r])[tid];
        #pragma unroll
        for (int r = 0; r < RPB; ++r) {
            int j = j0 + r;
            if (src[r]) {
                f4* dst = reinterpret_cast<f4*>(out + OFF_EMB + ((size_t)b * LL + j) * DD) + tid;
                __builtin_nontemporal_store(v[r], dst);
            }
        }
        return;
    }

    // ---- small outputs for batch b ----
    const int* trow  = tgt_ids + (size_t)b * TT;
    const int* tmrow = tgt_am  + (size_t)b * TT;
    float* amo  = out + OFF_AM  + (size_t)b * LL;
    float* tmo  = out + OFF_TM  + (size_t)b * LL;
    float* labo = out + OFF_LAB + (size_t)b * LL;

    for (int i = tid; i < LL; i += 256) {
        // ---- am (after both inserts at split) ----
        float amv;
        if (i < s) {
            amv = (i < PP) ? 1.0f : (float)mrow[i - PP];
        } else if (i < s2) {
            amv = 1.0f;                              // appended ones
        } else if (i < s2 + TT) {
            amv = (float)tmrow[i - s2];              // target attention mask
        } else {
            int k = i - AA - TT;
            amv = (k < PP) ? 1.0f : (float)mrow[k - PP];
        }
        amo[i] = amv;

        // ---- target_mask, shifted right by 1 ----
        float tmv = 0.0f;
        if (i > 0) {
            int k = i - 1 - s2;
            if (k >= 0 && k < TT) tmv = (float)tmrow[k];
        }
        tmo[i] = tmv;

        // ---- labels, shifted left by 1 (last = -1) ----
        float lv = -1.0f;
        if (i < LL - 1) {
            int u = i + 1 - s2;
            if (u >= 0 && u < TT && tmrow[u] == 1) lv = (float)trow[u];
        }
        labo[i] = lv;
    }

    // ---- target_ids: input shifted left by 1, last = -1; and split2 ----
    if (tid < TT) {
        float tv = (tid == TT - 1) ? -1.0f : (float)trow[tid + 1];
        out[OFF_TI + (size_t)b * TT + tid] = tv;
    }
    if (tid == 0) out[OFF_S2 + b] = (float)s2;
}

extern "C" void kernel_launch(void* const* d_in, const int* in_sizes, int n_in,
                              void* d_out, int out_size, void* d_ws, size_t ws_size,
                              hipStream_t stream) {
    const int*   input_ids = (const int*)d_in[0];
    const int*   attn_mask = (const int*)d_in[1];
    const int*   tgt_ids   = (const int*)d_in[2];
    const int*   tgt_am    = (const int*)d_in[3];
    const float* wte       = (const float*)d_in[4];
    const float* prep      = (const float*)d_in[5];
    const float* app       = (const float*)d_in[6];
    float* out = (float*)d_out;

    soft_emb_fused<<<dim3(NG + 1, BB), 256, 0, stream>>>(input_ids, attn_mask, tgt_ids, tgt_am,
                                                         wte, prep, app, out);
}

// Round 6
// 48.101 us; speedup vs baseline: 1.1085x; 1.0311x over previous
//
#include <hip/hip_runtime.h>
#include <climits>

// Problem constants
#define VV 50257
#define DD 1024
#define BB 16
#define SS 2048
#define PP 10
#define AA 5
#define TT 64
#define LL (PP + SS + TT + AA)   // 2127
#define RPB 8                    // rows per block
#define NG  ((LL + RPB - 1) / RPB) // 266 row-groups

// Output element offsets (float32 elements, outputs concatenated flat in return order)
#define OFF_EMB ((size_t)0)
#define OFF_AM  ((size_t)BB * LL * DD)
#define OFF_TM  (OFF_AM + (size_t)BB * LL)
#define OFF_TI  (OFF_TM + (size_t)BB * LL)
#define OFF_S2  (OFF_TI + (size_t)BB * TT)
#define OFF_LAB (OFF_S2 + (size_t)BB)

typedef float f4 __attribute__((ext_vector_type(4)));
typedef int   i4 __attribute__((ext_vector_type(4)));

// Per-row source pointer (layout after both inserts at split s)
static __device__ __forceinline__ const float*
row_src(int j, int b, int s, int s2,
        const int* __restrict__ input_ids, const int* __restrict__ tgt_ids,
        const float* __restrict__ wte, const float* __restrict__ prep,
        const float* __restrict__ app)
{
    if (j < s) {
        return (j < PP) ? (prep + (size_t)j * DD)
                        : (wte + (size_t)input_ids[(size_t)b * SS + (j - PP)] * DD);
    } else if (j < s2) {
        return app + (size_t)(j - s) * DD;
    } else if (j < s2 + TT) {
        return wte + (size_t)tgt_ids[(size_t)b * TT + (j - s2)] * DD;
    } else {
        int k = j - AA - TT;
        return (k < PP) ? (prep + (size_t)k * DD)
                        : (wte + (size_t)input_ids[(size_t)b * SS + (k - PP)] * DD);
    }
}

// Single fused kernel: grid (NG+1, BB), 256 threads.
//  Every block computes its batch's split via coalesced scan + ballot reduce (1 barrier).
//  blockIdx.x <  NG : copy RPB emb rows (independent float4 loads -> NT stores)
//  blockIdx.x == NG : all small outputs for batch b
__global__ void soft_emb_fused(const int* __restrict__ input_ids,  // (B,S)
                               const int* __restrict__ attn_mask,  // (B,S)
                               const int* __restrict__ tgt_ids,    // (B,T)
                               const int* __restrict__ tgt_am,     // (B,T)
                               const float* __restrict__ wte,      // (V,D)
                               const float* __restrict__ prep,     // (P,D)
                               const float* __restrict__ app,      // (A,D)
                               float* __restrict__ out)            // f32 flat
{
    const int g    = blockIdx.x;
    const int b    = blockIdx.y;
    const int tid  = threadIdx.x;
    const int lane = tid & 63;
    const int wid  = tid >> 6;

    // ---- split scan: 256 threads x 8 ints = 2048 = SS; ballot min, 1 barrier ----
    __shared__ int wmin[4];
    const int* mrow = attn_mask + (size_t)b * SS;
    int fz = INT_MAX;
    {
        const i4* m4 = reinterpret_cast<const i4*>(mrow) + tid * 2;
        i4 a = m4[0];
        i4 c = m4[1];
        int base = tid * 8;
        // first zero among my 8 (reverse order, min wins)
        if (c.w == 0) fz = base + 7;
        if (c.z == 0) fz = base + 6;
        if (c.y == 0) fz = base + 5;
        if (c.x == 0) fz = base + 4;
        if (a.w == 0) fz = base + 3;
        if (a.z == 0) fz = base + 2;
        if (a.y == 0) fz = base + 1;
        if (a.x == 0) fz = base + 0;
    }
    // lanes are ordered by position: first lane with a zero holds the wave min
    unsigned long long bal = __ballot(fz != INT_MAX);
    int wfz = INT_MAX;
    if (bal) {
        int sl = (int)__ffsll((unsigned long long)bal) - 1;
        wfz = __shfl(fz, sl);
    }
    if (lane == 0) wmin[wid] = wfz;
    __syncthreads();
    const int first0 = min(min(wmin[0], wmin[1]), min(wmin[2], wmin[3]));
    const int s  = (first0 == INT_MAX) ? 1 : (PP + first0 + 1);
    const int s2 = s + AA;

    if (g < NG) {
        const int j0 = g * RPB;
        const float* src[RPB];
        #pragma unroll
        for (int r = 0; r < RPB; ++r) {
            int j = j0 + r;
            src[r] = (j < LL) ? row_src(j, b, s, s2, input_ids, tgt_ids, wte, prep, app)
                              : nullptr;
        }
        f4 v[RPB];
        #pragma unroll
        for (int r = 0; r < RPB; ++r)
            if (src[r]) v[r] = reinterpret_cast<const f4*>(src[r])[tid];
        #pragma unroll
        for (int r = 0; r < RPB; ++r) {
            int j = j0 + r;
            if (src[r]) {
                f4* dst = reinterpret_cast<f4*>(out + OFF_EMB + ((size_t)b * LL + j) * DD) + tid;
                __builtin_nontemporal_store(v[r], dst);
            }
        }
        return;
    }

    // ---- small outputs for batch b ----
    const int* trow  = tgt_ids + (size_t)b * TT;
    const int* tmrow = tgt_am  + (size_t)b * TT;
    float* amo  = out + OFF_AM  + (size_t)b * LL;
    float* tmo  = out + OFF_TM  + (size_t)b * LL;
    float* labo = out + OFF_LAB + (size_t)b * LL;

    for (int i = tid; i < LL; i += 256) {
        // ---- am (after both inserts at split) ----
        float amv;
        if (i < s) {
            amv = (i < PP) ? 1.0f : (float)mrow[i - PP];
        } else if (i < s2) {
            amv = 1.0f;                              // appended ones
        } else if (i < s2 + TT) {
            amv = (float)tmrow[i - s2];              // target attention mask
        } else {
            int k = i - AA - TT;
            amv = (k < PP) ? 1.0f : (float)mrow[k - PP];
        }
        amo[i] = amv;

        // ---- target_mask, shifted right by 1 ----
        float tmv = 0.0f;
        if (i > 0) {
            int k = i - 1 - s2;
            if (k >= 0 && k < TT) tmv = (float)tmrow[k];
        }
        tmo[i] = tmv;

        // ---- labels, shifted left by 1 (last = -1) ----
        float lv = -1.0f;
        if (i < LL - 1) {
            int u = i + 1 - s2;
            if (u >= 0 && u < TT && tmrow[u] == 1) lv = (float)trow[u];
        }
        labo[i] = lv;
    }

    // ---- target_ids: input shifted left by 1, last = -1; and split2 ----
    if (tid < TT) {
        float tv = (tid == TT - 1) ? -1.0f : (float)trow[tid + 1];
        out[OFF_TI + (size_t)b * TT + tid] = tv;
    }
    if (tid == 0) out[OFF_S2 + b] = (float)s2;
}

extern "C" void kernel_launch(void* const* d_in, const int* in_sizes, int n_in,
                              void* d_out, int out_size, void* d_ws, size_t ws_size,
                              hipStream_t stream) {
    const int*   input_ids = (const int*)d_in[0];
    const int*   attn_mask = (const int*)d_in[1];
    const int*   tgt_ids   = (const int*)d_in[2];
    const int*   tgt_am    = (const int*)d_in[3];
    const float* wte       = (const float*)d_in[4];
    const float* prep      = (const float*)d_in[5];
    const float* app       = (const float*)d_in[6];
    float* out = (float*)d_out;

    soft_emb_fused<<<dim3(NG + 1, BB), 256, 0, stream>>>(input_ids, attn_mask, tgt_ids, tgt_am,
                                                         wte, prep, app, out);
}